// Round 1
// baseline (34.186 us; speedup 1.0000x reference)
//
#include <hip/hip_runtime.h>
#include <math.h>

#define NPTS 4096
#define NB 8
#define TOTAL (2*NB*NPTS)   // 65536 points across both sets
#define EPSF 1e-12f

// monotone float->uint key so atomicMin(uint) == float min (handles negatives)
__device__ __forceinline__ unsigned fkey(float x){
    unsigned b = __float_as_uint(x);
    return b ^ (unsigned)(((int)b >> 31) | (int)0x80000000);
}
__device__ __forceinline__ float fdecode(unsigned k){
    unsigned b = (k & 0x80000000u) ? (k ^ 0x80000000u) : ~k;
    return __uint_as_float(b);
}

// Kernel A: project all points to image plane, store (x, y, x^2+y^2, 0),
// and init the min-key buffer.
__global__ void project_kernel(const float* __restrict__ pred,
                               const float* __restrict__ gt,
                               const float* __restrict__ P,
                               float4* __restrict__ proj,
                               unsigned* __restrict__ minbuf){
    int i = blockIdx.x * 256 + threadIdx.x;   // [0, 65536)
    minbuf[i] = 0xFFFFFFFFu;
    int set = i >> 15;          // 0 = gt, 1 = pred
    int b   = (i >> 12) & 7;
    int n   = i & 4095;
    const float* src = set ? pred : gt;
    const float* p3  = src + (size_t)(b * NPTS + n) * 3;
    float x = p3[0], y = p3[1], z = p3[2];
    const float* Pb = P + b * 12;
    float px = Pb[0]*x + Pb[1]*y + Pb[2]*z  + Pb[3];
    float py = Pb[4]*x + Pb[5]*y + Pb[6]*z  + Pb[7];
    float pz = Pb[8]*x + Pb[9]*y + Pb[10]*z + Pb[11];
    float ix = px / pz;
    float iy = py / pz;
    proj[i] = make_float4(ix, iy, ix*ix + iy*iy, 0.0f);
}

// Kernel B: for each query point, min over a 256-candidate chunk of
// t = |b|^2 - 2 a.b  (query's |a|^2 added in the epilogue).
// grid = 2 dirs x 8 batches x 2 query-halves x 16 chunks = 512 blocks, 256 thr.
#define QPT 8
#define CCH 256
__global__ void chamfer_kernel(const float4* __restrict__ proj,
                               unsigned* __restrict__ minbuf){
    __shared__ float4 cand[CCH];
    int bid   = blockIdx.x;
    int chunk = bid & 15;
    int qhalf = (bid >> 4) & 1;
    int b     = (bid >> 5) & 7;
    int dir   = (bid >> 8) & 1;
    int t = threadIdx.x;

    int qbase = dir * (NB*NPTS) + b * NPTS + qhalf * (QPT*256);
    int cbase = (1 - dir) * (NB*NPTS) + b * NPTS + chunk * CCH;

    // stage candidate chunk into LDS as (-2x, -2y, |c|^2)
    float4 c = proj[cbase + t];
    cand[t] = make_float4(-2.0f*c.x, -2.0f*c.y, c.z, 0.0f);
    __syncthreads();

    float ax[QPT], ay[QPT], mn[QPT];
    #pragma unroll
    for (int q = 0; q < QPT; ++q){
        float4 a = proj[qbase + t + q*256];
        ax[q] = a.x; ay[q] = a.y; mn[q] = 3.4e38f;
    }

    #pragma unroll 4
    for (int ci = 0; ci < CCH; ++ci){
        float4 cd = cand[ci];          // broadcast ds_read_b128
        #pragma unroll
        for (int q = 0; q < QPT; ++q){
            float tt = fmaf(ax[q], cd.x, cd.z);
            tt = fmaf(ay[q], cd.y, tt);
            mn[q] = fminf(mn[q], tt);
        }
    }

    #pragma unroll
    for (int q = 0; q < QPT; ++q){
        atomicMin(minbuf + qbase + t + q*256, fkey(mn[q]));
    }
}

// Kernel C1: per-block partial sums of sqrt(max(|a|^2 + min_t, eps))
__global__ void reduce1(const float4* __restrict__ proj,
                        const unsigned* __restrict__ minbuf,
                        float* __restrict__ partials){
    __shared__ float sm[256];
    int t = threadIdx.x;
    float s = 0.0f;
    for (int i = blockIdx.x * 256 + t; i < TOTAL; i += gridDim.x * 256){
        float d2 = fdecode(minbuf[i]) + proj[i].z;
        s += sqrtf(fmaxf(d2, EPSF));
    }
    sm[t] = s; __syncthreads();
    #pragma unroll
    for (int o = 128; o > 0; o >>= 1){
        if (t < o) sm[t] += sm[t + o];
        __syncthreads();
    }
    if (t == 0) partials[blockIdx.x] = sm[0];
}

// Kernel C2: final sum of 256 partials, scale by 1/(B*N) = 1/32768
__global__ void reduce2(const float* __restrict__ partials,
                        float* __restrict__ out){
    __shared__ float sm[256];
    int t = threadIdx.x;
    sm[t] = partials[t];
    __syncthreads();
    #pragma unroll
    for (int o = 128; o > 0; o >>= 1){
        if (t < o) sm[t] += sm[t + o];
        __syncthreads();
    }
    if (t == 0) out[0] = sm[0] * (1.0f / 32768.0f);
}

extern "C" void kernel_launch(void* const* d_in, const int* in_sizes, int n_in,
                              void* d_out, int out_size, void* d_ws, size_t ws_size,
                              hipStream_t stream) {
    const float* pred = (const float*)d_in[0];
    const float* gt   = (const float*)d_in[1];
    const float* P    = (const float*)d_in[2];
    float* out = (float*)d_out;

    float4*   proj     = (float4*)d_ws;                                   // 1 MB
    unsigned* minbuf   = (unsigned*)((char*)d_ws + (size_t)TOTAL*16);     // 256 KB
    float*    partials = (float*)((char*)d_ws + (size_t)TOTAL*16 + (size_t)TOTAL*4);

    project_kernel<<<TOTAL/256, 256, 0, stream>>>(pred, gt, P, proj, minbuf);
    chamfer_kernel<<<512, 256, 0, stream>>>(proj, minbuf);
    reduce1<<<256, 256, 0, stream>>>(proj, minbuf, partials);
    reduce2<<<1, 256, 0, stream>>>(partials, out);
}

// Round 2
// 27.988 us; speedup vs baseline: 1.2214x; 1.2214x over previous
//
#include <hip/hip_runtime.h>
#include <math.h>

#define NPTS 4096
#define NB 8
#define NQTOT (2*NB*NPTS)   // 65536 query points across both directions
#define EPSF 1e-12f
#define NCHUNK 16
#define CCH 256             // candidates per chunk
#define QPT 8               // queries per thread

typedef float f32x2 __attribute__((ext_vector_type(2)));

// t = {fma(a.lo, b.lo, c.lo), fma(a.hi, b.lo, c.lo)}  (b,c word0 broadcast)
static __device__ __forceinline__ f32x2 pk_fma_bx(f32x2 a, f32x2 b, f32x2 c){
    f32x2 d;
    asm("v_pk_fma_f32 %0, %1, %2, %3 op_sel:[0,0,0] op_sel_hi:[1,0,0]"
        : "=v"(d) : "v"(a), "v"(b), "v"(c));
    return d;
}
// t = {fma(a.lo, b.hi, c.lo), fma(a.hi, b.hi, c.hi)}  (b word1 broadcast, c packed)
static __device__ __forceinline__ f32x2 pk_fma_by(f32x2 a, f32x2 b, f32x2 c){
    f32x2 d;
    asm("v_pk_fma_f32 %0, %1, %2, %3 op_sel:[0,1,0] op_sel_hi:[1,1,1]"
        : "=v"(d) : "v"(a), "v"(b), "v"(c));
    return d;
}
static __device__ __forceinline__ float fmin3(float a, float b, float c){
    float d;
    asm("v_min3_f32 %0, %1, %2, %3" : "=v"(d) : "v"(a), "v"(b), "v"(c));
    return d;
}

static __device__ __forceinline__ void project_pt(const float* __restrict__ p3,
                                                  const float* __restrict__ Pb,
                                                  float& ix, float& iy){
    float x = p3[0], y = p3[1], z = p3[2];
    float px = fmaf(Pb[0],x, fmaf(Pb[1],y, fmaf(Pb[2],z,  Pb[3])));
    float py = fmaf(Pb[4],x, fmaf(Pb[5],y, fmaf(Pb[6],z,  Pb[7])));
    float pz = fmaf(Pb[8],x, fmaf(Pb[9],y, fmaf(Pb[10],z, Pb[11])));
    ix = px / pz;
    iy = py / pz;
}

// One block = (dir, batch, query-half, candidate-chunk).
// Projects its own 256 candidates + 2048 queries, then per-query min of
// t = |c|^2 - 2 a.c over the chunk; stores full d2 = min_t + |a|^2 to
// minpart[chunk][global_query]. No atomics — deterministic.
__global__ __launch_bounds__(256) void chamfer_fused(
        const float* __restrict__ pred, const float* __restrict__ gt,
        const float* __restrict__ P, float* __restrict__ minpart){
    __shared__ float4 cand[CCH];   // {-2x, -2y, |c|^2, 0}
    int bid   = blockIdx.x;
    int chunk = bid & 15;
    int qhalf = (bid >> 4) & 1;
    int b     = (bid >> 5) & 7;
    int dir   = (bid >> 8) & 1;
    int t = threadIdx.x;

    const float* Pb   = P + b * 12;
    const float* qsrc = dir ? pred : gt;
    const float* csrc = dir ? gt : pred;

    // project this block's candidate chunk into LDS
    {
        const float* p3 = csrc + (size_t)(b*NPTS + chunk*CCH + t) * 3;
        float cx, cy; project_pt(p3, Pb, cx, cy);
        cand[t] = make_float4(-2.0f*cx, -2.0f*cy, fmaf(cx,cx, cy*cy), 0.0f);
    }

    // project this thread's 8 queries (packed in pairs for pk_fma)
    f32x2 axp[4], ayp[4];
    float a2[QPT];
    #pragma unroll
    for (int q = 0; q < QPT; ++q){
        int qi = qhalf*(QPT*256) + q*256 + t;
        const float* p3 = qsrc + (size_t)(b*NPTS + qi) * 3;
        float ix, iy; project_pt(p3, Pb, ix, iy);
        axp[q>>1][q&1] = ix;
        ayp[q>>1][q&1] = iy;
        a2[q] = fmaf(ix,ix, iy*iy);
    }
    float mn[QPT];
    #pragma unroll
    for (int q = 0; q < QPT; ++q) mn[q] = 3.4e38f;

    __syncthreads();

    #pragma unroll 4
    for (int ci = 0; ci < CCH; ci += 2){
        float4 cd0 = cand[ci];
        float4 cd1 = cand[ci+1];
        f32x2 c0lo = {cd0.x, cd0.y}, c0hi = {cd0.z, cd0.w};
        f32x2 c1lo = {cd1.x, cd1.y}, c1hi = {cd1.z, cd1.w};
        #pragma unroll
        for (int p = 0; p < 4; ++p){
            f32x2 t0 = pk_fma_bx(axp[p], c0lo, c0hi);
            t0 = pk_fma_by(ayp[p], c0lo, t0);
            f32x2 t1 = pk_fma_bx(axp[p], c1lo, c1hi);
            t1 = pk_fma_by(ayp[p], c1lo, t1);
            mn[2*p]   = fmin3(t0.x, t1.x, mn[2*p]);
            mn[2*p+1] = fmin3(t0.y, t1.y, mn[2*p+1]);
        }
    }

    int gq = dir*(NB*NPTS) + b*NPTS + qhalf*(QPT*256) + t;
    #pragma unroll
    for (int q = 0; q < QPT; ++q){
        minpart[(size_t)chunk*NQTOT + gq + q*256] = mn[q] + a2[q];
    }
}

// 16-way min across chunks, sqrt, per-block partial sum.
__global__ __launch_bounds__(256) void reduce_min_sum(
        const float* __restrict__ minpart, float* __restrict__ partials){
    __shared__ float sm[256];
    int t = threadIdx.x;
    int i = blockIdx.x * 256 + t;   // 256 blocks cover 65536 queries
    float m0 = minpart[i];
    #pragma unroll
    for (int c = 1; c < NCHUNK; ++c) m0 = fminf(m0, minpart[(size_t)c*NQTOT + i]);
    float s = sqrtf(fmaxf(m0, EPSF));
    sm[t] = s; __syncthreads();
    #pragma unroll
    for (int o = 128; o > 0; o >>= 1){
        if (t < o) sm[t] += sm[t + o];
        __syncthreads();
    }
    if (t == 0) partials[blockIdx.x] = sm[0];
}

__global__ void reduce_final(const float* __restrict__ partials,
                             float* __restrict__ out){
    __shared__ float sm[256];
    int t = threadIdx.x;
    sm[t] = partials[t];
    __syncthreads();
    #pragma unroll
    for (int o = 128; o > 0; o >>= 1){
        if (t < o) sm[t] += sm[t + o];
        __syncthreads();
    }
    if (t == 0) out[0] = sm[0] * (1.0f / 32768.0f);
}

extern "C" void kernel_launch(void* const* d_in, const int* in_sizes, int n_in,
                              void* d_out, int out_size, void* d_ws, size_t ws_size,
                              hipStream_t stream) {
    const float* pred = (const float*)d_in[0];
    const float* gt   = (const float*)d_in[1];
    const float* P    = (const float*)d_in[2];
    float* out = (float*)d_out;

    float* minpart  = (float*)d_ws;                                        // 4 MB
    float* partials = (float*)((char*)d_ws + (size_t)NCHUNK*NQTOT*4);      // 1 KB

    chamfer_fused<<<512, 256, 0, stream>>>(pred, gt, P, minpart);
    reduce_min_sum<<<256, 256, 0, stream>>>(minpart, partials);
    reduce_final<<<1, 256, 0, stream>>>(partials, out);
}